// Round 13
// baseline (101.003 us; speedup 1.0000x reference)
//
#include <hip/hip_runtime.h>

#define S_LEN 4096
#define BATCH 2
#define EMB   768
#define NH    12
#define HDIM  64
#define WIN   256

using f32x4  = __attribute__((ext_vector_type(4))) float;
using bf16x8 = __attribute__((ext_vector_type(8))) short;
using u16x4  = __attribute__((ext_vector_type(4))) unsigned short;
using u16x8  = __attribute__((ext_vector_type(8))) unsigned short;

#define AS1 __attribute__((address_space(1)))
#define AS3 __attribute__((address_space(3)))

__device__ __forceinline__ unsigned short f2bf(float x) {
    unsigned int u = __float_as_uint(x);
    return (unsigned short)((u + 0x7fffu + ((u >> 16) & 1u)) >> 16);
}
__device__ __forceinline__ unsigned short f2bf_fast(float x) {
    return (unsigned short)((__float_as_uint(x) + 0x8000u) >> 16);
}

// ---------------- fused fp32 -> bf16 convert (hs + 3 weights in ONE launch) ----------------
__global__ void cvt_all_kernel(const float* __restrict__ hs, const float* __restrict__ w0,
                               const float* __restrict__ w1, const float* __restrict__ w2,
                               unsigned short* __restrict__ ohs, unsigned short* __restrict__ o0,
                               unsigned short* __restrict__ o1, unsigned short* __restrict__ o2) {
    int blk = blockIdx.x;
    const float* in;
    unsigned short* out;
    int i;
    if (blk < 3072) { in = hs; out = ohs; i = blk * 256 + threadIdx.x; if (i >= 786432) return; }
    else {
        int wsel = (blk - 3072) / 288;
        int wblk = (blk - 3072) % 288;
        in  = (wsel == 0) ? w0 : (wsel == 1) ? w1 : w2;
        out = (wsel == 0) ? o0 : (wsel == 1) ? o1 : o2;
        i = wblk * 256 + threadIdx.x;
        if (i >= 73728) return;
    }
    const float4* p = reinterpret_cast<const float4*>(in) + (size_t)i * 2;
    float4 a = p[0];
    float4 b = p[1];
    u16x8 o;
    o[0] = f2bf(a.x); o[1] = f2bf(a.y); o[2] = f2bf(a.z); o[3] = f2bf(a.w);
    o[4] = f2bf(b.x); o[5] = f2bf(b.y); o[6] = f2bf(b.z); o[7] = f2bf(b.w);
    reinterpret_cast<u16x8*>(out)[i] = o;
}

// ---------------- fused QKV GEMM (r7 structure: best measured, 52.2 us) ----------------
#define NKT (EMB / 32)   // 24

__global__ __launch_bounds__(256) void qkv_gemm(
    const unsigned short* __restrict__ A,
    const unsigned short* __restrict__ Wq,
    const unsigned short* __restrict__ Wk,
    const unsigned short* __restrict__ Wv,
    const float* __restrict__ bq,
    const float* __restrict__ bk,
    const float* __restrict__ bv,
    unsigned short* __restrict__ qo,   // [B][H][S][HD]
    unsigned short* __restrict__ ko,   // [B][H][S][HD]
    unsigned short* __restrict__ vo)   // [B][H][HD][S]  (transposed)
{
    __shared__ unsigned short As[2][128 * 32];
    __shared__ unsigned short Bs[2][128 * 32];

    const int tid  = threadIdx.x;
    const int lane = tid & 63;
    const int wave = tid >> 6;

    const int mblk = blockIdx.x;
    const int nblk = blockIdx.y;
    const int wsel = nblk / 6;
    const int nloc0 = (nblk % 6) * 128;
    const unsigned short* Wp = (wsel == 0) ? Wq : ((wsel == 1) ? Wk : Wv);
    const int wm = wave >> 1, wn = wave & 1;

    f32x4 acc[4][4];
#pragma unroll
    for (int i = 0; i < 4; ++i)
#pragma unroll
        for (int j = 0; j < 4; ++j)
            acc[i][j] = (f32x4){0.f, 0.f, 0.f, 0.f};

    const int frow = lane & 15;
    const int g    = lane >> 4;

    const char* Abase = (const char*)(A  + (size_t)(mblk * 128) * EMB);
    const char* Bbase = (const char*)(Wp + (size_t)nloc0 * EMB);

    const int srow = tid >> 2;
    const int pb   = tid & 3;
    const int sblk = pb ^ ((srow >> 1) & 3);

#define GLDS(gp, lp) __builtin_amdgcn_global_load_lds((const AS1 unsigned int*)(gp), (AS3 unsigned int*)(lp), 16, 0, 0)
#define STG(q, t) do {                                                                                   \
    GLDS(Abase + (size_t)srow * 1536 + (t) * 64 + sblk * 16,        &As[q][srow * 32 + pb * 8]);         \
    GLDS(Abase + (size_t)(64 + srow) * 1536 + (t) * 64 + sblk * 16, &As[q][(64 + srow) * 32 + pb * 8]);  \
    GLDS(Bbase + (size_t)srow * 1536 + (t) * 64 + sblk * 16,        &Bs[q][srow * 32 + pb * 8]);         \
    GLDS(Bbase + (size_t)(64 + srow) * 1536 + (t) * 64 + sblk * 16, &Bs[q][(64 + srow) * 32 + pb * 8]);  \
} while (0)

    auto rdA = [&](int q, int mi) -> bf16x8 {
        int r = wm * 64 + mi * 16 + frow;
        return *reinterpret_cast<const bf16x8*>(&As[q][r * 32 + (g ^ ((r >> 1) & 3)) * 8]);
    };
    auto rdB = [&](int q, int ni) -> bf16x8 {
        int r = wn * 64 + ni * 16 + frow;
        return *reinterpret_cast<const bf16x8*>(&Bs[q][r * 32 + (g ^ ((r >> 1) & 3)) * 8]);
    };

#define KLOOP(SW) do {                                                                        \
    STG(0, 0);                                                                                \
    asm volatile("s_waitcnt vmcnt(0)" ::: "memory");                                          \
    __syncthreads();                                                                          \
    int cur = 0;                                                                              \
    _Pragma("unroll 1")                                                                       \
    for (int t = 0; t < NKT; ++t) {                                                           \
        if (t + 1 < NKT) STG(cur ^ 1, t + 1);                                                 \
        bf16x8 afr[4], bfr[4];                                                                \
        _Pragma("unroll") for (int ni = 0; ni < 4; ++ni) bfr[ni] = rdB(cur, ni);              \
        _Pragma("unroll") for (int mi = 0; mi < 4; ++mi) afr[mi] = rdA(cur, mi);              \
        __builtin_amdgcn_s_setprio(1);                                                        \
        _Pragma("unroll") for (int mi = 0; mi < 4; ++mi)                                      \
            _Pragma("unroll") for (int ni = 0; ni < 4; ++ni)                                  \
                acc[mi][ni] = (SW)                                                            \
                    ? __builtin_amdgcn_mfma_f32_16x16x32_bf16(bfr[ni], afr[mi], acc[mi][ni], 0, 0, 0)  \
                    : __builtin_amdgcn_mfma_f32_16x16x32_bf16(afr[mi], bfr[ni], acc[mi][ni], 0, 0, 0); \
        __builtin_amdgcn_s_setprio(0);                                                        \
        if (t + 1 < NKT) {                                                                    \
            asm volatile("s_waitcnt vmcnt(0)" ::: "memory");                                  \
            __syncthreads();                                                                  \
            cur ^= 1;                                                                         \
        }                                                                                     \
    }                                                                                         \
} while (0)

    if (wsel < 2) {
        KLOOP(1);
        const float* bias = (wsel == 0) ? bq : bk;
        unsigned short* op = (wsel == 0) ? qo : ko;
        const float qs = (wsel == 0) ? 0.125f : 1.0f;
#pragma unroll
        for (int mi = 0; mi < 4; ++mi) {
            int m = mblk * 128 + wm * 64 + mi * 16 + frow;
            int b = m >> 12, s = m & 4095;
#pragma unroll
            for (int ni = 0; ni < 4; ++ni) {
                int n0 = nloc0 + wn * 64 + ni * 16 + g * 4;
                float4 bb = *reinterpret_cast<const float4*>(&bias[n0]);
                int h = n0 >> 6, hd0 = n0 & 63;
                u16x4 pk;
                pk[0] = f2bf((acc[mi][ni][0] + bb.x) * qs);
                pk[1] = f2bf((acc[mi][ni][1] + bb.y) * qs);
                pk[2] = f2bf((acc[mi][ni][2] + bb.z) * qs);
                pk[3] = f2bf((acc[mi][ni][3] + bb.w) * qs);
                *reinterpret_cast<u16x4*>(&op[((size_t)(b * NH + h) * S_LEN + s) * HDIM + hd0]) = pk;
            }
        }
    } else {
        KLOOP(0);
#pragma unroll
        for (int mi = 0; mi < 4; ++mi) {
            int m0 = mblk * 128 + wm * 64 + mi * 16 + g * 4;
            int b = m0 >> 12, s0 = m0 & 4095;
#pragma unroll
            for (int ni = 0; ni < 4; ++ni) {
                int n = nloc0 + wn * 64 + ni * 16 + frow;
                float bb = bv[n];
                int h = n >> 6, hd = n & 63;
                u16x4 pk;
                pk[0] = f2bf(acc[mi][ni][0] + bb);
                pk[1] = f2bf(acc[mi][ni][1] + bb);
                pk[2] = f2bf(acc[mi][ni][2] + bb);
                pk[3] = f2bf(acc[mi][ni][3] + bb);
                *reinterpret_cast<u16x4*>(&vo[((size_t)(b * NH + h) * HDIM + hd) * S_LEN + s0]) = pk;
            }
        }
    }
}

// ---------------- banded flash attention: 4 waves x 32 q-rows (K/V frag reads SHARED) ----------------
// DS-pipe-bound diagnosis: 8 waves all read identical K/V fragments (8x redundant).
// 4 waves x 2 q-subtiles: each K-frag/V-frag ds_read_b128 feeds 2x the MFMA work
// -> per-CU DS traffic -30%. Same verified 16x16 layouts, fixed-max softmax.
#define QB   128
#define KC   64
#define NCHQ ((QB + 2 * WIN) / KC)   // 10

// 256 threads: rows 0-31 + 32-63 per buffer, 8 threads/row (16B each), pre-swizzled source
#define STAGE_ATT(buf, ks) do {                                                              \
    __builtin_amdgcn_global_load_lds(                                                        \
        (const AS1 unsigned int*)(kp + (size_t)((ks) + srow) * HDIM + gblk * 8),             \
        (AS3 unsigned int*)&Ksm[buf][wave * 512], 16, 0, 0);                                 \
    __builtin_amdgcn_global_load_lds(                                                        \
        (const AS1 unsigned int*)(kp + (size_t)((ks) + 32 + srow) * HDIM + gblk * 8),        \
        (AS3 unsigned int*)&Ksm[buf][2048 + wave * 512], 16, 0, 0);                          \
    __builtin_amdgcn_global_load_lds(                                                        \
        (const AS1 unsigned int*)(vp + (size_t)srow * S_LEN + (ks) + gblk * 8),              \
        (AS3 unsigned int*)&Vsm[buf][wave * 512], 16, 0, 0);                                 \
    __builtin_amdgcn_global_load_lds(                                                        \
        (const AS1 unsigned int*)(vp + (size_t)(32 + srow) * S_LEN + (ks) + gblk * 8),       \
        (AS3 unsigned int*)&Vsm[buf][2048 + wave * 512], 16, 0, 0);                          \
} while (0)

__global__ __launch_bounds__(256) void banded_attn(
    const unsigned short* __restrict__ qg,   // [B][H][S][HD]
    const unsigned short* __restrict__ kg,   // [B][H][S][HD]
    const unsigned short* __restrict__ vtg,  // [B][H][HD][S]
    float* __restrict__ out)                 // [B][S][E]
{
    __shared__ unsigned short Ksm[2][KC * HDIM];     // 2 x 8 KB
    __shared__ unsigned short Vsm[2][HDIM * KC];     // 2 x 8 KB
    __shared__ unsigned short Psm[4][32 * KC];       // 4 x 4 KB  (48 KB total)

    const int tid  = threadIdx.x;
    const int wave = tid >> 6, lane = tid & 63;
    const int qb = blockIdx.x * QB;
    const int h  = blockIdx.y, b = blockIdx.z;

    const unsigned short* qp = qg  + (size_t)(b * NH + h) * S_LEN * HDIM;
    const unsigned short* kp = kg  + (size_t)(b * NH + h) * S_LEN * HDIM;
    const unsigned short* vp = vtg + (size_t)(b * NH + h) * HDIM * S_LEN;

    const int frow = lane & 15;
    const int g    = lane >> 4;
    const int fcol = g * 8;

    const int srow = tid >> 3;               // 0..31
    const int gblk = (tid & 7) ^ (srow & 7); // pre-swizzled 16B-block index

    const int qw = qb + wave * 32;           // wave's first q-row (32 rows per wave)

    // Q fragments: [qs][slice]
    bf16x8 qf[2][2];
#pragma unroll
    for (int qs = 0; qs < 2; ++qs) {
        const unsigned short* qr = qp + (size_t)(qw + qs * 16 + frow) * HDIM;
        qf[qs][0] = *reinterpret_cast<const bf16x8*>(qr + fcol);
        qf[qs][1] = *reinterpret_cast<const bf16x8*>(qr + 32 + fcol);
    }

    float l_part[2][4];
    f32x4 o_acc[2][4];
#pragma unroll
    for (int qs = 0; qs < 2; ++qs)
#pragma unroll
        for (int r = 0; r < 4; ++r) l_part[qs][r] = 0.f;
#pragma unroll
    for (int qs = 0; qs < 2; ++qs)
#pragma unroll
        for (int ni = 0; ni < 4; ++ni) o_acc[qs][ni] = (f32x4){0.f, 0.f, 0.f, 0.f};

    const int c_start = (qb < WIN) ? ((WIN - qb) >> 6) : 0;
    const int c_end   = min(NCHQ, (S_LEN + WIN - qb) >> 6);

    const int w_lo = qw - WIN;               // active iff ks+63 >= w_lo && ks <= w_hi
    const int w_hi = qw + 31 + WIN;

    STAGE_ATT(0, qb - WIN + c_start * KC);
    asm volatile("s_waitcnt vmcnt(0)" ::: "memory");
    __syncthreads();

    int cur = 0;
    for (int c = c_start; c < c_end; ++c) {
        const int ks = qb - WIN + c * KC;
        if (c + 1 < c_end) STAGE_ATT(cur ^ 1, ks + KC);

        const bool active = (ks + KC - 1 >= w_lo) && (ks <= w_hi);
        if (active) {
            // ---- scores: 32 q x 64 keys per wave; K-frags shared across both q-subtiles ----
            f32x4 sc[2][4];
#pragma unroll
            for (int qs = 0; qs < 2; ++qs)
#pragma unroll
                for (int ni = 0; ni < 4; ++ni) sc[qs][ni] = (f32x4){0.f, 0.f, 0.f, 0.f};
#pragma unroll
            for (int ni = 0; ni < 4; ++ni) {
                int krow = ni * 16 + frow;
                int sw   = (krow & 7) << 3;
                bf16x8 kf0 = *reinterpret_cast<const bf16x8*>(&Ksm[cur][krow * KC + (fcol ^ sw)]);
                bf16x8 kf1 = *reinterpret_cast<const bf16x8*>(&Ksm[cur][krow * KC + ((32 + fcol) ^ sw)]);
#pragma unroll
                for (int qs = 0; qs < 2; ++qs) {
                    sc[qs][ni] = __builtin_amdgcn_mfma_f32_16x16x32_bf16(qf[qs][0], kf0, sc[qs][ni], 0, 0, 0);
                    sc[qs][ni] = __builtin_amdgcn_mfma_f32_16x16x32_bf16(qf[qs][1], kf1, sc[qs][ni], 0, 0, 0);
                }
            }

            // ---- fixed-max softmax; full-window chunks skip the mask ----
            const bool full = (ks >= qw - 225) && (ks <= qw + 193);
            float pm[2][4][4];
            if (full) {
#pragma unroll
                for (int qs = 0; qs < 2; ++qs)
#pragma unroll
                    for (int ni = 0; ni < 4; ++ni)
#pragma unroll
                        for (int r = 0; r < 4; ++r)
                            pm[qs][ni][r] = __expf(sc[qs][ni][r]);
            } else {
#pragma unroll
                for (int qs = 0; qs < 2; ++qs) {
                    int qrow0s = qw + qs * 16 + g * 4;
#pragma unroll
                    for (int ni = 0; ni < 4; ++ni) {
                        int d0 = qrow0s - (ks + ni * 16 + frow);
#pragma unroll
                        for (int r = 0; r < 4; ++r) {
                            bool valid = (unsigned)(d0 + r + WIN) <= (unsigned)(2 * WIN);
                            pm[qs][ni][r] = valid ? __expf(sc[qs][ni][r]) : 0.f;
                        }
                    }
                }
            }
#pragma unroll
            for (int qs = 0; qs < 2; ++qs)
#pragma unroll
                for (int r = 0; r < 4; ++r) {
                    l_part[qs][r] += (pm[qs][0][r] + pm[qs][1][r]) + (pm[qs][2][r] + pm[qs][3][r]);
                    int prow = qs * 16 + g * 4 + r;
                    int swz  = ((g * 4 + r) & 7) << 3;
#pragma unroll
                    for (int ni = 0; ni < 4; ++ni)
                        Psm[wave][prow * KC + ((ni * 16 + frow) ^ swz)] = f2bf_fast(pm[qs][ni][r]);
                }

            asm volatile("s_waitcnt lgkmcnt(0)" ::: "memory");
            __builtin_amdgcn_sched_barrier(0);

            // ---- PV: V-frags shared across both q-subtiles ----
            bf16x8 pf[2][2];
#pragma unroll
            for (int qs = 0; qs < 2; ++qs) {
                int sw = (frow & 7) << 3;
#pragma unroll
                for (int kk = 0; kk < 2; ++kk)
                    pf[qs][kk] = *reinterpret_cast<const bf16x8*>(
                        &Psm[wave][(qs * 16 + frow) * KC + ((kk * 32 + fcol) ^ sw)]);
            }
#pragma unroll
            for (int ni = 0; ni < 4; ++ni) {
                int vrow = ni * 16 + frow;
                int sw   = (vrow & 7) << 3;
#pragma unroll
                for (int kk = 0; kk < 2; ++kk) {
                    bf16x8 vf = *reinterpret_cast<const bf16x8*>(&Vsm[cur][vrow * KC + ((kk * 32 + fcol) ^ sw)]);
#pragma unroll
                    for (int qs = 0; qs < 2; ++qs)
                        o_acc[qs][ni] = __builtin_amdgcn_mfma_f32_16x16x32_bf16(pf[qs][kk], vf, o_acc[qs][ni], 0, 0, 0);
                }
            }
        }

        asm volatile("s_waitcnt vmcnt(0)" ::: "memory");
        __syncthreads();
        cur ^= 1;
    }

    // ---- finalize: reduce l across the 16-lane group (keys), divide, store fp32 ----
#pragma unroll
    for (int d = 1; d < 16; d <<= 1)
#pragma unroll
        for (int qs = 0; qs < 2; ++qs)
#pragma unroll
            for (int r = 0; r < 4; ++r)
                l_part[qs][r] += __shfl_xor(l_part[qs][r], d, 64);

#pragma unroll
    for (int qs = 0; qs < 2; ++qs) {
        int qrow0s = qw + qs * 16 + g * 4;
#pragma unroll
        for (int r = 0; r < 4; ++r) {
            float inv = 1.0f / l_part[qs][r];
            int s = qrow0s + r;
            size_t obase = ((size_t)b * S_LEN + s) * EMB + h * HDIM;
#pragma unroll
            for (int ni = 0; ni < 4; ++ni)
                out[obase + ni * 16 + frow] = o_acc[qs][ni][r] * inv;
        }
    }
}

// ---------------- launcher ----------------
extern "C" void kernel_launch(void* const* d_in, const int* in_sizes, int n_in,
                              void* d_out, int out_size, void* d_ws, size_t ws_size,
                              hipStream_t stream) {
    const float* hs = (const float*)d_in[0];
    const float* Wq = (const float*)d_in[1];
    const float* Wk = (const float*)d_in[2];
    const float* Wv = (const float*)d_in[3];
    const float* bq = (const float*)d_in[4];
    const float* bk = (const float*)d_in[5];
    const float* bv = (const float*)d_in[6];
    float* out = (float*)d_out;

    char* w = (char*)d_ws;
    unsigned short* hs_bf = (unsigned short*)w;                       // 12,582,912 B
    unsigned short* wq_bf = (unsigned short*)(w + 12582912);
    unsigned short* wk_bf = wq_bf + 589824;
    unsigned short* wv_bf = wk_bf + 589824;
    unsigned short* q_ws  = (unsigned short*)(w + 12582912 + 3 * 1179648);
    unsigned short* k_ws  = q_ws + 6291456;
    unsigned short* v_ws  = k_ws + 6291456;

    cvt_all_kernel<<<3936, 256, 0, stream>>>(hs, Wq, Wk, Wv, hs_bf, wq_bf, wk_bf, wv_bf);

    qkv_gemm<<<dim3(64, 18), 256, 0, stream>>>(hs_bf, wq_bf, wk_bf, wv_bf,
                                               bq, bk, bv, q_ws, k_ws, v_ws);

    banded_attn<<<dim3(S_LEN / QB, NH, BATCH), 256, 0, stream>>>(q_ws, k_ws, v_ws, out);
}

// Round 14
// 93.938 us; speedup vs baseline: 1.0752x; 1.0752x over previous
//
#include <hip/hip_runtime.h>

#define S_LEN 4096
#define BATCH 2
#define EMB   768
#define NH    12
#define HDIM  64
#define WIN   256

using f32x4  = __attribute__((ext_vector_type(4))) float;
using bf16x8 = __attribute__((ext_vector_type(8))) short;
using u16x4  = __attribute__((ext_vector_type(4))) unsigned short;
using u16x8  = __attribute__((ext_vector_type(8))) unsigned short;

#define AS1 __attribute__((address_space(1)))
#define AS3 __attribute__((address_space(3)))

__device__ __forceinline__ unsigned short f2bf(float x) {
    unsigned int u = __float_as_uint(x);
    return (unsigned short)((u + 0x7fffu + ((u >> 16) & 1u)) >> 16);
}
__device__ __forceinline__ unsigned short f2bf_fast(float x) {
    return (unsigned short)((__float_as_uint(x) + 0x8000u) >> 16);
}

// ---------------- fused fp32 -> bf16 convert (hs + 3 weights, 16 elems/thread) ----------------
// blocks [0,1536) -> hs; [1536,1680) -> Wq; [1680,1824) -> Wk; [1824,1968) -> Wv
__global__ void cvt_all_kernel(const float* __restrict__ hs, const float* __restrict__ w0,
                               const float* __restrict__ w1, const float* __restrict__ w2,
                               unsigned short* __restrict__ ohs, unsigned short* __restrict__ o0,
                               unsigned short* __restrict__ o1, unsigned short* __restrict__ o2) {
    int blk = blockIdx.x;
    const float* in;
    unsigned short* out;
    int i2;
    if (blk < 1536) { in = hs; out = ohs; i2 = blk * 256 + threadIdx.x; if (i2 >= 393216) return; }
    else {
        int wsel = (blk - 1536) / 144;
        int wblk = (blk - 1536) % 144;
        in  = (wsel == 0) ? w0 : (wsel == 1) ? w1 : w2;
        out = (wsel == 0) ? o0 : (wsel == 1) ? o1 : o2;
        i2 = wblk * 256 + threadIdx.x;
        if (i2 >= 36864) return;
    }
#pragma unroll
    for (int half = 0; half < 2; ++half) {
        int i = i2 * 2 + half;
        const float4* p = reinterpret_cast<const float4*>(in) + (size_t)i * 2;
        float4 a = p[0];
        float4 b = p[1];
        u16x8 o;
        o[0] = f2bf(a.x); o[1] = f2bf(a.y); o[2] = f2bf(a.z); o[3] = f2bf(a.w);
        o[4] = f2bf(b.x); o[5] = f2bf(b.y); o[6] = f2bf(b.z); o[7] = f2bf(b.w);
        reinterpret_cast<u16x8*>(out)[i] = o;
    }
}

// ---------------- fused QKV GEMM (r7 structure: best measured, 52.2 us) ----------------
#define NKT (EMB / 32)   // 24

__global__ __launch_bounds__(256) void qkv_gemm(
    const unsigned short* __restrict__ A,
    const unsigned short* __restrict__ Wq,
    const unsigned short* __restrict__ Wk,
    const unsigned short* __restrict__ Wv,
    const float* __restrict__ bq,
    const float* __restrict__ bk,
    const float* __restrict__ bv,
    unsigned short* __restrict__ qo,   // [B][H][S][HD]
    unsigned short* __restrict__ ko,   // [B][H][S][HD]
    unsigned short* __restrict__ vo)   // [B][H][HD][S]  (transposed)
{
    __shared__ unsigned short As[2][128 * 32];
    __shared__ unsigned short Bs[2][128 * 32];

    const int tid  = threadIdx.x;
    const int lane = tid & 63;
    const int wave = tid >> 6;

    const int mblk = blockIdx.x;
    const int nblk = blockIdx.y;
    const int wsel = nblk / 6;
    const int nloc0 = (nblk % 6) * 128;
    const unsigned short* Wp = (wsel == 0) ? Wq : ((wsel == 1) ? Wk : Wv);
    const int wm = wave >> 1, wn = wave & 1;

    f32x4 acc[4][4];
#pragma unroll
    for (int i = 0; i < 4; ++i)
#pragma unroll
        for (int j = 0; j < 4; ++j)
            acc[i][j] = (f32x4){0.f, 0.f, 0.f, 0.f};

    const int frow = lane & 15;
    const int g    = lane >> 4;

    const char* Abase = (const char*)(A  + (size_t)(mblk * 128) * EMB);
    const char* Bbase = (const char*)(Wp + (size_t)nloc0 * EMB);

    const int srow = tid >> 2;
    const int pb   = tid & 3;
    const int sblk = pb ^ ((srow >> 1) & 3);

#define GLDS(gp, lp) __builtin_amdgcn_global_load_lds((const AS1 unsigned int*)(gp), (AS3 unsigned int*)(lp), 16, 0, 0)
#define STG(q, t) do {                                                                                   \
    GLDS(Abase + (size_t)srow * 1536 + (t) * 64 + sblk * 16,        &As[q][srow * 32 + pb * 8]);         \
    GLDS(Abase + (size_t)(64 + srow) * 1536 + (t) * 64 + sblk * 16, &As[q][(64 + srow) * 32 + pb * 8]);  \
    GLDS(Bbase + (size_t)srow * 1536 + (t) * 64 + sblk * 16,        &Bs[q][srow * 32 + pb * 8]);         \
    GLDS(Bbase + (size_t)(64 + srow) * 1536 + (t) * 64 + sblk * 16, &Bs[q][(64 + srow) * 32 + pb * 8]);  \
} while (0)

    auto rdA = [&](int q, int mi) -> bf16x8 {
        int r = wm * 64 + mi * 16 + frow;
        return *reinterpret_cast<const bf16x8*>(&As[q][r * 32 + (g ^ ((r >> 1) & 3)) * 8]);
    };
    auto rdB = [&](int q, int ni) -> bf16x8 {
        int r = wn * 64 + ni * 16 + frow;
        return *reinterpret_cast<const bf16x8*>(&Bs[q][r * 32 + (g ^ ((r >> 1) & 3)) * 8]);
    };

#define KLOOP(SW) do {                                                                        \
    STG(0, 0);                                                                                \
    asm volatile("s_waitcnt vmcnt(0)" ::: "memory");                                          \
    __syncthreads();                                                                          \
    int cur = 0;                                                                              \
    _Pragma("unroll 1")                                                                       \
    for (int t = 0; t < NKT; ++t) {                                                           \
        if (t + 1 < NKT) STG(cur ^ 1, t + 1);                                                 \
        bf16x8 afr[4], bfr[4];                                                                \
        _Pragma("unroll") for (int ni = 0; ni < 4; ++ni) bfr[ni] = rdB(cur, ni);              \
        _Pragma("unroll") for (int mi = 0; mi < 4; ++mi) afr[mi] = rdA(cur, mi);              \
        __builtin_amdgcn_s_setprio(1);                                                        \
        _Pragma("unroll") for (int mi = 0; mi < 4; ++mi)                                      \
            _Pragma("unroll") for (int ni = 0; ni < 4; ++ni)                                  \
                acc[mi][ni] = (SW)                                                            \
                    ? __builtin_amdgcn_mfma_f32_16x16x32_bf16(bfr[ni], afr[mi], acc[mi][ni], 0, 0, 0)  \
                    : __builtin_amdgcn_mfma_f32_16x16x32_bf16(afr[mi], bfr[ni], acc[mi][ni], 0, 0, 0); \
        __builtin_amdgcn_s_setprio(0);                                                        \
        if (t + 1 < NKT) {                                                                    \
            asm volatile("s_waitcnt vmcnt(0)" ::: "memory");                                  \
            __syncthreads();                                                                  \
            cur ^= 1;                                                                         \
        }                                                                                     \
    }                                                                                         \
} while (0)

    if (wsel < 2) {
        KLOOP(1);
        const float* bias = (wsel == 0) ? bq : bk;
        unsigned short* op = (wsel == 0) ? qo : ko;
        const float qs = (wsel == 0) ? 0.125f : 1.0f;
#pragma unroll
        for (int mi = 0; mi < 4; ++mi) {
            int m = mblk * 128 + wm * 64 + mi * 16 + frow;
            int b = m >> 12, s = m & 4095;
#pragma unroll
            for (int ni = 0; ni < 4; ++ni) {
                int n0 = nloc0 + wn * 64 + ni * 16 + g * 4;
                float4 bb = *reinterpret_cast<const float4*>(&bias[n0]);
                int h = n0 >> 6, hd0 = n0 & 63;
                u16x4 pk;
                pk[0] = f2bf((acc[mi][ni][0] + bb.x) * qs);
                pk[1] = f2bf((acc[mi][ni][1] + bb.y) * qs);
                pk[2] = f2bf((acc[mi][ni][2] + bb.z) * qs);
                pk[3] = f2bf((acc[mi][ni][3] + bb.w) * qs);
                *reinterpret_cast<u16x4*>(&op[((size_t)(b * NH + h) * S_LEN + s) * HDIM + hd0]) = pk;
            }
        }
    } else {
        KLOOP(0);
#pragma unroll
        for (int mi = 0; mi < 4; ++mi) {
            int m0 = mblk * 128 + wm * 64 + mi * 16 + g * 4;
            int b = m0 >> 12, s0 = m0 & 4095;
#pragma unroll
            for (int ni = 0; ni < 4; ++ni) {
                int n = nloc0 + wn * 64 + ni * 16 + frow;
                float bb = bv[n];
                int h = n >> 6, hd = n & 63;
                u16x4 pk;
                pk[0] = f2bf(acc[mi][ni][0] + bb);
                pk[1] = f2bf(acc[mi][ni][1] + bb);
                pk[2] = f2bf(acc[mi][ni][2] + bb);
                pk[3] = f2bf(acc[mi][ni][3] + bb);
                *reinterpret_cast<u16x4*>(&vo[((size_t)(b * NH + h) * HDIM + hd) * S_LEN + s0]) = pk;
            }
        }
    }
}

// ---------------- banded flash attention (r12 exact: 8 waves x 16 q-rows, best measured ~30.5 us) ----------------
#define QB   128
#define KC   64
#define NCHQ ((QB + 2 * WIN) / KC)   // 10

#define STAGE_ATT(buf, ks) do {                                                              \
    const unsigned short* kr_ = kp + (size_t)((ks) + srow) * HDIM + gblk * 8;                \
    __builtin_amdgcn_global_load_lds(                                                        \
        (const AS1 unsigned int*)kr_,                                                        \
        (AS3 unsigned int*)&Ksm[buf][wave * 512], 16, 0, 0);                                 \
    const unsigned short* vr_ = vp + (size_t)srow * S_LEN + (ks) + gblk * 8;                 \
    __builtin_amdgcn_global_load_lds(                                                        \
        (const AS1 unsigned int*)vr_,                                                        \
        (AS3 unsigned int*)&Vsm[buf][wave * 512], 16, 0, 0);                                 \
} while (0)

__global__ __launch_bounds__(512) void banded_attn(
    const unsigned short* __restrict__ qg,   // [B][H][S][HD]
    const unsigned short* __restrict__ kg,   // [B][H][S][HD]
    const unsigned short* __restrict__ vtg,  // [B][H][HD][S]
    float* __restrict__ out)                 // [B][S][E]
{
    __shared__ unsigned short Ksm[2][KC * HDIM];
    __shared__ unsigned short Vsm[2][HDIM * KC];
    __shared__ unsigned short Psm[8][16 * KC];

    const int tid  = threadIdx.x;
    const int wave = tid >> 6, lane = tid & 63;
    const int qb = blockIdx.x * QB;
    const int h  = blockIdx.y, b = blockIdx.z;

    const unsigned short* qp = qg  + (size_t)(b * NH + h) * S_LEN * HDIM;
    const unsigned short* kp = kg  + (size_t)(b * NH + h) * S_LEN * HDIM;
    const unsigned short* vp = vtg + (size_t)(b * NH + h) * HDIM * S_LEN;

    const int frow = lane & 15;
    const int g    = lane >> 4;
    const int fcol = g * 8;

    const int srow = tid >> 3;               // 0..63
    const int gblk = (tid & 7) ^ (srow & 7); // pre-swizzled 16B-block index

    bf16x8 qf[2];
    {
        const unsigned short* qr = qp + (size_t)(qb + wave * 16 + frow) * HDIM;
        qf[0] = *reinterpret_cast<const bf16x8*>(qr + fcol);
        qf[1] = *reinterpret_cast<const bf16x8*>(qr + 32 + fcol);
    }

    float l_part[4];
    f32x4 o_acc[4];
#pragma unroll
    for (int r = 0; r < 4; ++r) l_part[r] = 0.f;
#pragma unroll
    for (int ni = 0; ni < 4; ++ni) o_acc[ni] = (f32x4){0.f, 0.f, 0.f, 0.f};

    const int c_start = (qb < WIN) ? ((WIN - qb) >> 6) : 0;
    const int c_end   = min(NCHQ, (S_LEN + WIN - qb) >> 6);
    const int qw    = qb + wave * 16;
    const int qrow0 = qw + g * 4;

    const int w_lo = qw - WIN;
    const int w_hi = qw + 15 + WIN;

    int kb[4];
#pragma unroll
    for (int ni = 0; ni < 4; ++ni) kb[ni] = ni * 16 + frow;
    unsigned short* prow_p[4];
    int swz_r[4];
#pragma unroll
    for (int r = 0; r < 4; ++r) {
        int prow = g * 4 + r;
        prow_p[r] = &Psm[wave][prow * KC];
        swz_r[r]  = (prow & 7) << 3;
    }

    STAGE_ATT(0, qb - WIN + c_start * KC);
    asm volatile("s_waitcnt vmcnt(0)" ::: "memory");
    __syncthreads();

    int cur = 0;
    for (int c = c_start; c < c_end; ++c) {
        const int ks = qb - WIN + c * KC;
        if (c + 1 < c_end) STAGE_ATT(cur ^ 1, ks + KC);

        const bool active = (ks + KC - 1 >= w_lo) && (ks <= w_hi);
        if (active) {
            f32x4 sc[4];
#pragma unroll
            for (int ni = 0; ni < 4; ++ni) sc[ni] = (f32x4){0.f, 0.f, 0.f, 0.f};
#pragma unroll
            for (int ni = 0; ni < 4; ++ni) {
                int krow = ni * 16 + frow;
                int sw   = (krow & 7) << 3;
                bf16x8 kf0 = *reinterpret_cast<const bf16x8*>(&Ksm[cur][krow * KC + (fcol ^ sw)]);
                bf16x8 kf1 = *reinterpret_cast<const bf16x8*>(&Ksm[cur][krow * KC + ((32 + fcol) ^ sw)]);
                sc[ni] = __builtin_amdgcn_mfma_f32_16x16x32_bf16(qf[0], kf0, sc[ni], 0, 0, 0);
                sc[ni] = __builtin_amdgcn_mfma_f32_16x16x32_bf16(qf[1], kf1, sc[ni], 0, 0, 0);
            }

            const bool full = (ks >= qw - 241) && (ks <= qw + 193);
            float pm[4][4];
            if (full) {
#pragma unroll
                for (int ni = 0; ni < 4; ++ni)
#pragma unroll
                    for (int r = 0; r < 4; ++r)
                        pm[ni][r] = __expf(sc[ni][r]);
            } else {
#pragma unroll
                for (int ni = 0; ni < 4; ++ni) {
                    int d0 = qrow0 - (ks + kb[ni]);
#pragma unroll
                    for (int r = 0; r < 4; ++r) {
                        bool valid = (unsigned)(d0 + r + WIN) <= (unsigned)(2 * WIN);
                        pm[ni][r] = valid ? __expf(sc[ni][r]) : 0.f;
                    }
                }
            }
#pragma unroll
            for (int r = 0; r < 4; ++r) {
                l_part[r] += (pm[0][r] + pm[1][r]) + (pm[2][r] + pm[3][r]);
#pragma unroll
                for (int ni = 0; ni < 4; ++ni)
                    prow_p[r][kb[ni] ^ swz_r[r]] = f2bf_fast(pm[ni][r]);
            }

            asm volatile("s_waitcnt lgkmcnt(0)" ::: "memory");
            __builtin_amdgcn_sched_barrier(0);

            bf16x8 pf[2];
#pragma unroll
            for (int kk = 0; kk < 2; ++kk) {
                int sw = (frow & 7) << 3;
                pf[kk] = *reinterpret_cast<const bf16x8*>(&Psm[wave][frow * KC + ((kk * 32 + fcol) ^ sw)]);
            }
#pragma unroll
            for (int ni = 0; ni < 4; ++ni) {
                int vrow = ni * 16 + frow;
                int sw   = (vrow & 7) << 3;
#pragma unroll
                for (int kk = 0; kk < 2; ++kk) {
                    bf16x8 vf = *reinterpret_cast<const bf16x8*>(&Vsm[cur][vrow * KC + ((kk * 32 + fcol) ^ sw)]);
                    o_acc[ni] = __builtin_amdgcn_mfma_f32_16x16x32_bf16(pf[kk], vf, o_acc[ni], 0, 0, 0);
                }
            }
        }

        asm volatile("s_waitcnt vmcnt(0)" ::: "memory");
        __syncthreads();
        cur ^= 1;
    }

#pragma unroll
    for (int d = 1; d < 16; d <<= 1)
#pragma unroll
        for (int r = 0; r < 4; ++r)
            l_part[r] += __shfl_xor(l_part[r], d, 64);

#pragma unroll
    for (int r = 0; r < 4; ++r) {
        float inv = 1.0f / l_part[r];
        int s = qrow0 + r;
        size_t obase = ((size_t)b * S_LEN + s) * EMB + h * HDIM;
#pragma unroll
        for (int ni = 0; ni < 4; ++ni)
            out[obase + ni * 16 + frow] = o_acc[ni][r] * inv;
    }
}

// ---------------- launcher ----------------
extern "C" void kernel_launch(void* const* d_in, const int* in_sizes, int n_in,
                              void* d_out, int out_size, void* d_ws, size_t ws_size,
                              hipStream_t stream) {
    const float* hs = (const float*)d_in[0];
    const float* Wq = (const float*)d_in[1];
    const float* Wk = (const float*)d_in[2];
    const float* Wv = (const float*)d_in[3];
    const float* bq = (const float*)d_in[4];
    const float* bk = (const float*)d_in[5];
    const float* bv = (const float*)d_in[6];
    float* out = (float*)d_out;

    char* w = (char*)d_ws;
    unsigned short* hs_bf = (unsigned short*)w;                       // 12,582,912 B
    unsigned short* wq_bf = (unsigned short*)(w + 12582912);
    unsigned short* wk_bf = wq_bf + 589824;
    unsigned short* wv_bf = wk_bf + 589824;
    unsigned short* q_ws  = (unsigned short*)(w + 12582912 + 3 * 1179648);
    unsigned short* k_ws  = q_ws + 6291456;
    unsigned short* v_ws  = k_ws + 6291456;

    cvt_all_kernel<<<1968, 256, 0, stream>>>(hs, Wq, Wk, Wv, hs_bf, wq_bf, wk_bf, wv_bf);

    qkv_gemm<<<dim3(64, 18), 256, 0, stream>>>(hs_bf, wq_bf, wk_bf, wv_bf,
                                               bq, bk, bv, q_ws, k_ws, v_ws);

    banded_attn<<<dim3(S_LEN / QB, NH, BATCH), 512, 0, stream>>>(q_ws, k_ws, v_ws, out);
}

// Round 15
// 89.724 us; speedup vs baseline: 1.1257x; 1.0470x over previous
//
#include <hip/hip_runtime.h>

#define S_LEN 4096
#define BATCH 2
#define EMB   768
#define NH    12
#define HDIM  64
#define WIN   256

using f32x4  = __attribute__((ext_vector_type(4))) float;
using bf16x8 = __attribute__((ext_vector_type(8))) short;
using u16x4  = __attribute__((ext_vector_type(4))) unsigned short;
using u16x8  = __attribute__((ext_vector_type(8))) unsigned short;

#define AS1 __attribute__((address_space(1)))
#define AS3 __attribute__((address_space(3)))

__device__ __forceinline__ unsigned short f2bf(float x) {
    unsigned int u = __float_as_uint(x);
    return (unsigned short)((u + 0x7fffu + ((u >> 16) & 1u)) >> 16);
}
__device__ __forceinline__ unsigned short f2bf_fast(float x) {
    return (unsigned short)((__float_as_uint(x) + 0x8000u) >> 16);
}

// ---------------- fused fp32 -> bf16 convert (hs + 3 weights, 16 elems/thread) ----------------
__global__ void cvt_all_kernel(const float* __restrict__ hs, const float* __restrict__ w0,
                               const float* __restrict__ w1, const float* __restrict__ w2,
                               unsigned short* __restrict__ ohs, unsigned short* __restrict__ o0,
                               unsigned short* __restrict__ o1, unsigned short* __restrict__ o2) {
    int blk = blockIdx.x;
    const float* in;
    unsigned short* out;
    int i2;
    if (blk < 1536) { in = hs; out = ohs; i2 = blk * 256 + threadIdx.x; if (i2 >= 393216) return; }
    else {
        int wsel = (blk - 1536) / 144;
        int wblk = (blk - 1536) % 144;
        in  = (wsel == 0) ? w0 : (wsel == 1) ? w1 : w2;
        out = (wsel == 0) ? o0 : (wsel == 1) ? o1 : o2;
        i2 = wblk * 256 + threadIdx.x;
        if (i2 >= 36864) return;
    }
#pragma unroll
    for (int half = 0; half < 2; ++half) {
        int i = i2 * 2 + half;
        const float4* p = reinterpret_cast<const float4*>(in) + (size_t)i * 2;
        float4 a = p[0];
        float4 b = p[1];
        u16x8 o;
        o[0] = f2bf(a.x); o[1] = f2bf(a.y); o[2] = f2bf(a.z); o[3] = f2bf(a.w);
        o[4] = f2bf(b.x); o[5] = f2bf(b.y); o[6] = f2bf(b.z); o[7] = f2bf(b.w);
        reinterpret_cast<u16x8*>(out)[i] = o;
    }
}

// ---------------- fused QKV GEMM (r7 structure: best measured, 52.2 us) ----------------
#define NKT (EMB / 32)   // 24

__global__ __launch_bounds__(256) void qkv_gemm(
    const unsigned short* __restrict__ A,
    const unsigned short* __restrict__ Wq,
    const unsigned short* __restrict__ Wk,
    const unsigned short* __restrict__ Wv,
    const float* __restrict__ bq,
    const float* __restrict__ bk,
    const float* __restrict__ bv,
    unsigned short* __restrict__ qo,   // [B][H][S][HD]
    unsigned short* __restrict__ ko,   // [B][H][S][HD]
    unsigned short* __restrict__ vo)   // [B][H][HD][S]  (transposed)
{
    __shared__ unsigned short As[2][128 * 32];
    __shared__ unsigned short Bs[2][128 * 32];

    const int tid  = threadIdx.x;
    const int lane = tid & 63;
    const int wave = tid >> 6;

    const int mblk = blockIdx.x;
    const int nblk = blockIdx.y;
    const int wsel = nblk / 6;
    const int nloc0 = (nblk % 6) * 128;
    const unsigned short* Wp = (wsel == 0) ? Wq : ((wsel == 1) ? Wk : Wv);
    const int wm = wave >> 1, wn = wave & 1;

    f32x4 acc[4][4];
#pragma unroll
    for (int i = 0; i < 4; ++i)
#pragma unroll
        for (int j = 0; j < 4; ++j)
            acc[i][j] = (f32x4){0.f, 0.f, 0.f, 0.f};

    const int frow = lane & 15;
    const int g    = lane >> 4;

    const char* Abase = (const char*)(A  + (size_t)(mblk * 128) * EMB);
    const char* Bbase = (const char*)(Wp + (size_t)nloc0 * EMB);

    const int srow = tid >> 2;
    const int pb   = tid & 3;
    const int sblk = pb ^ ((srow >> 1) & 3);

#define GLDS(gp, lp) __builtin_amdgcn_global_load_lds((const AS1 unsigned int*)(gp), (AS3 unsigned int*)(lp), 16, 0, 0)
#define STG(q, t) do {                                                                                   \
    GLDS(Abase + (size_t)srow * 1536 + (t) * 64 + sblk * 16,        &As[q][srow * 32 + pb * 8]);         \
    GLDS(Abase + (size_t)(64 + srow) * 1536 + (t) * 64 + sblk * 16, &As[q][(64 + srow) * 32 + pb * 8]);  \
    GLDS(Bbase + (size_t)srow * 1536 + (t) * 64 + sblk * 16,        &Bs[q][srow * 32 + pb * 8]);         \
    GLDS(Bbase + (size_t)(64 + srow) * 1536 + (t) * 64 + sblk * 16, &Bs[q][(64 + srow) * 32 + pb * 8]);  \
} while (0)

    auto rdA = [&](int q, int mi) -> bf16x8 {
        int r = wm * 64 + mi * 16 + frow;
        return *reinterpret_cast<const bf16x8*>(&As[q][r * 32 + (g ^ ((r >> 1) & 3)) * 8]);
    };
    auto rdB = [&](int q, int ni) -> bf16x8 {
        int r = wn * 64 + ni * 16 + frow;
        return *reinterpret_cast<const bf16x8*>(&Bs[q][r * 32 + (g ^ ((r >> 1) & 3)) * 8]);
    };

#define KLOOP(SW) do {                                                                        \
    STG(0, 0);                                                                                \
    asm volatile("s_waitcnt vmcnt(0)" ::: "memory");                                          \
    __syncthreads();                                                                          \
    int cur = 0;                                                                              \
    _Pragma("unroll 1")                                                                       \
    for (int t = 0; t < NKT; ++t) {                                                           \
        if (t + 1 < NKT) STG(cur ^ 1, t + 1);                                                 \
        bf16x8 afr[4], bfr[4];                                                                \
        _Pragma("unroll") for (int ni = 0; ni < 4; ++ni) bfr[ni] = rdB(cur, ni);              \
        _Pragma("unroll") for (int mi = 0; mi < 4; ++mi) afr[mi] = rdA(cur, mi);              \
        __builtin_amdgcn_s_setprio(1);                                                        \
        _Pragma("unroll") for (int mi = 0; mi < 4; ++mi)                                      \
            _Pragma("unroll") for (int ni = 0; ni < 4; ++ni)                                  \
                acc[mi][ni] = (SW)                                                            \
                    ? __builtin_amdgcn_mfma_f32_16x16x32_bf16(bfr[ni], afr[mi], acc[mi][ni], 0, 0, 0)  \
                    : __builtin_amdgcn_mfma_f32_16x16x32_bf16(afr[mi], bfr[ni], acc[mi][ni], 0, 0, 0); \
        __builtin_amdgcn_s_setprio(0);                                                        \
        if (t + 1 < NKT) {                                                                    \
            asm volatile("s_waitcnt vmcnt(0)" ::: "memory");                                  \
            __syncthreads();                                                                  \
            cur ^= 1;                                                                         \
        }                                                                                     \
    }                                                                                         \
} while (0)

    if (wsel < 2) {
        KLOOP(1);
        const float* bias = (wsel == 0) ? bq : bk;
        unsigned short* op = (wsel == 0) ? qo : ko;
        const float qs = (wsel == 0) ? 0.125f : 1.0f;
#pragma unroll
        for (int mi = 0; mi < 4; ++mi) {
            int m = mblk * 128 + wm * 64 + mi * 16 + frow;
            int b = m >> 12, s = m & 4095;
#pragma unroll
            for (int ni = 0; ni < 4; ++ni) {
                int n0 = nloc0 + wn * 64 + ni * 16 + g * 4;
                float4 bb = *reinterpret_cast<const float4*>(&bias[n0]);
                int h = n0 >> 6, hd0 = n0 & 63;
                u16x4 pk;
                pk[0] = f2bf((acc[mi][ni][0] + bb.x) * qs);
                pk[1] = f2bf((acc[mi][ni][1] + bb.y) * qs);
                pk[2] = f2bf((acc[mi][ni][2] + bb.z) * qs);
                pk[3] = f2bf((acc[mi][ni][3] + bb.w) * qs);
                *reinterpret_cast<u16x4*>(&op[((size_t)(b * NH + h) * S_LEN + s) * HDIM + hd0]) = pk;
            }
        }
    } else {
        KLOOP(0);
#pragma unroll
        for (int mi = 0; mi < 4; ++mi) {
            int m0 = mblk * 128 + wm * 64 + mi * 16 + g * 4;
            int b = m0 >> 12, s0 = m0 & 4095;
#pragma unroll
            for (int ni = 0; ni < 4; ++ni) {
                int n = nloc0 + wn * 64 + ni * 16 + frow;
                float bb = bv[n];
                int h = n >> 6, hd = n & 63;
                u16x4 pk;
                pk[0] = f2bf(acc[mi][ni][0] + bb);
                pk[1] = f2bf(acc[mi][ni][1] + bb);
                pk[2] = f2bf(acc[mi][ni][2] + bb);
                pk[3] = f2bf(acc[mi][ni][3] + bb);
                *reinterpret_cast<u16x4*>(&vo[((size_t)(b * NH + h) * HDIM + hd) * S_LEN + s0]) = pk;
            }
        }
    }
}

// ---------------- banded flash attention: swapped QK^T -> packed P writes ----------------
// sc = mfma(K, Q) gives lane (g,frow): S[key = ks + ni*16 + g*4 + r][q = qw + frow]
// -> the 4 reg values are 4 CONSECUTIVE keys at one q -> P written as 4x u16x4
// (ds_write_b64) instead of 16 scalar u16 writes. kf/qf reads, pf reads, PV, and
// output layout are all byte-identical to the verified r12 kernel.
#define QB   128
#define KC   64
#define NCHQ ((QB + 2 * WIN) / KC)   // 10

#define STAGE_ATT(buf, ks) do {                                                              \
    const unsigned short* kr_ = kp + (size_t)((ks) + srow) * HDIM + gblk * 8;                \
    __builtin_amdgcn_global_load_lds(                                                        \
        (const AS1 unsigned int*)kr_,                                                        \
        (AS3 unsigned int*)&Ksm[buf][wave * 512], 16, 0, 0);                                 \
    const unsigned short* vr_ = vp + (size_t)srow * S_LEN + (ks) + gblk * 8;                 \
    __builtin_amdgcn_global_load_lds(                                                        \
        (const AS1 unsigned int*)vr_,                                                        \
        (AS3 unsigned int*)&Vsm[buf][wave * 512], 16, 0, 0);                                 \
} while (0)

__global__ __launch_bounds__(512) void banded_attn(
    const unsigned short* __restrict__ qg,   // [B][H][S][HD]
    const unsigned short* __restrict__ kg,   // [B][H][S][HD]
    const unsigned short* __restrict__ vtg,  // [B][H][HD][S]
    float* __restrict__ out)                 // [B][S][E]
{
    __shared__ unsigned short Ksm[2][KC * HDIM];
    __shared__ unsigned short Vsm[2][HDIM * KC];
    __shared__ unsigned short Psm[8][16 * KC];

    const int tid  = threadIdx.x;
    const int wave = tid >> 6, lane = tid & 63;
    const int qb = blockIdx.x * QB;
    const int h  = blockIdx.y, b = blockIdx.z;

    const unsigned short* qp = qg  + (size_t)(b * NH + h) * S_LEN * HDIM;
    const unsigned short* kp = kg  + (size_t)(b * NH + h) * S_LEN * HDIM;
    const unsigned short* vp = vtg + (size_t)(b * NH + h) * HDIM * S_LEN;

    const int frow = lane & 15;
    const int g    = lane >> 4;
    const int fcol = g * 8;

    const int srow = tid >> 3;               // 0..63
    const int gblk = (tid & 7) ^ (srow & 7); // pre-swizzled 16B-block index

    bf16x8 qf[2];
    {
        const unsigned short* qr = qp + (size_t)(qb + wave * 16 + frow) * HDIM;
        qf[0] = *reinterpret_cast<const bf16x8*>(qr + fcol);
        qf[1] = *reinterpret_cast<const bf16x8*>(qr + 32 + fcol);
    }

    float l_loc = 0.f;                       // partial l for q = qw + frow (this thread's 16 keys/chunk)
    f32x4 o_acc[4];
#pragma unroll
    for (int ni = 0; ni < 4; ++ni) o_acc[ni] = (f32x4){0.f, 0.f, 0.f, 0.f};

    const int c_start = (qb < WIN) ? ((WIN - qb) >> 6) : 0;
    const int c_end   = min(NCHQ, (S_LEN + WIN - qb) >> 6);
    const int qw    = qb + wave * 16;
    const int qrow0 = qw + g * 4;

    const int w_lo = qw - WIN;
    const int w_hi = qw + 15 + WIN;

    // P write slots: row = frow (q), logical cols ni*16 + g*4 .. +3, XOR-swizzled.
    // (x^s)+r == (x+r)^s for 4-aligned x, r<4, s multiple of 8 -> read side unchanged.
    unsigned short* pwr[4];
#pragma unroll
    for (int ni = 0; ni < 4; ++ni)
        pwr[ni] = &Psm[wave][frow * KC + ((ni * 16 + g * 4) ^ ((frow & 7) << 3))];

    STAGE_ATT(0, qb - WIN + c_start * KC);
    asm volatile("s_waitcnt vmcnt(0)" ::: "memory");
    __syncthreads();

    int cur = 0;
    for (int c = c_start; c < c_end; ++c) {
        const int ks = qb - WIN + c * KC;
        if (c + 1 < c_end) STAGE_ATT(cur ^ 1, ks + KC);

        const bool active = (ks + KC - 1 >= w_lo) && (ks <= w_hi);
        if (active) {
            // ---- S^T = K Q^T: lane holds S[key = ks+ni*16+g*4+r][q = qw+frow] ----
            f32x4 sc[4];
#pragma unroll
            for (int ni = 0; ni < 4; ++ni) sc[ni] = (f32x4){0.f, 0.f, 0.f, 0.f};
#pragma unroll
            for (int ni = 0; ni < 4; ++ni) {
                int krow = ni * 16 + frow;
                int sw   = (krow & 7) << 3;
                bf16x8 kf0 = *reinterpret_cast<const bf16x8*>(&Ksm[cur][krow * KC + (fcol ^ sw)]);
                bf16x8 kf1 = *reinterpret_cast<const bf16x8*>(&Ksm[cur][krow * KC + ((32 + fcol) ^ sw)]);
                sc[ni] = __builtin_amdgcn_mfma_f32_16x16x32_bf16(kf0, qf[0], sc[ni], 0, 0, 0);
                sc[ni] = __builtin_amdgcn_mfma_f32_16x16x32_bf16(kf1, qf[1], sc[ni], 0, 0, 0);
            }

            const bool full = (ks >= qw - 241) && (ks <= qw + 193);
            float pm[4][4];
            if (full) {
#pragma unroll
                for (int ni = 0; ni < 4; ++ni)
#pragma unroll
                    for (int r = 0; r < 4; ++r)
                        pm[ni][r] = __expf(sc[ni][r]);
            } else {
#pragma unroll
                for (int ni = 0; ni < 4; ++ni) {
                    int d0 = (qw + frow) - (ks + ni * 16 + g * 4);   // q - key at r=0
#pragma unroll
                    for (int r = 0; r < 4; ++r) {
                        bool valid = (unsigned)(d0 - r + WIN) <= (unsigned)(2 * WIN);
                        pm[ni][r] = valid ? __expf(sc[ni][r]) : 0.f;
                    }
                }
            }
            // row-sum (q = qw+frow) + packed P writes (4x ds_write_b64)
#pragma unroll
            for (int ni = 0; ni < 4; ++ni) {
                l_loc += (pm[ni][0] + pm[ni][1]) + (pm[ni][2] + pm[ni][3]);
                u16x4 pk;
                pk[0] = f2bf_fast(pm[ni][0]);
                pk[1] = f2bf_fast(pm[ni][1]);
                pk[2] = f2bf_fast(pm[ni][2]);
                pk[3] = f2bf_fast(pm[ni][3]);
                *reinterpret_cast<u16x4*>(pwr[ni]) = pk;
            }

            asm volatile("s_waitcnt lgkmcnt(0)" ::: "memory");
            __builtin_amdgcn_sched_barrier(0);

            // ---- PV: unchanged (pf reads byte-identical to r12) ----
            bf16x8 pf[2];
#pragma unroll
            for (int kk = 0; kk < 2; ++kk) {
                int sw = (frow & 7) << 3;
                pf[kk] = *reinterpret_cast<const bf16x8*>(&Psm[wave][frow * KC + ((kk * 32 + fcol) ^ sw)]);
            }
#pragma unroll
            for (int ni = 0; ni < 4; ++ni) {
                int vrow = ni * 16 + frow;
                int sw   = (vrow & 7) << 3;
#pragma unroll
                for (int kk = 0; kk < 2; ++kk) {
                    bf16x8 vf = *reinterpret_cast<const bf16x8*>(&Vsm[cur][vrow * KC + ((kk * 32 + fcol) ^ sw)]);
                    o_acc[ni] = __builtin_amdgcn_mfma_f32_16x16x32_bf16(pf[kk], vf, o_acc[ni], 0, 0, 0);
                }
            }
        }

        asm volatile("s_waitcnt vmcnt(0)" ::: "memory");
        __syncthreads();
        cur ^= 1;
    }

    // ---- finalize: l_loc holds partial over this thread's 16 keys/chunk at q = qw+frow;
    // reduce across the 4 g-groups (lane bits 4,5), then broadcast per output row.
    l_loc += __shfl_xor(l_loc, 16, 64);
    l_loc += __shfl_xor(l_loc, 32, 64);

#pragma unroll
    for (int r = 0; r < 4; ++r) {
        float lr  = __shfl(l_loc, g * 4 + r, 64);   // l for q = qw + g*4 + r
        float inv = 1.0f / lr;
        int s = qrow0 + r;
        size_t obase = ((size_t)b * S_LEN + s) * EMB + h * HDIM;
#pragma unroll
        for (int ni = 0; ni < 4; ++ni)
            out[obase + ni * 16 + frow] = o_acc[ni][r] * inv;
    }
}

// ---------------- launcher ----------------
extern "C" void kernel_launch(void* const* d_in, const int* in_sizes, int n_in,
                              void* d_out, int out_size, void* d_ws, size_t ws_size,
                              hipStream_t stream) {
    const float* hs = (const float*)d_in[0];
    const float* Wq = (const float*)d_in[1];
    const float* Wk = (const float*)d_in[2];
    const float* Wv = (const float*)d_in[3];
    const float* bq = (const float*)d_in[4];
    const float* bk = (const float*)d_in[5];
    const float* bv = (const float*)d_in[6];
    float* out = (float*)d_out;

    char* w = (char*)d_ws;
    unsigned short* hs_bf = (unsigned short*)w;                       // 12,582,912 B
    unsigned short* wq_bf = (unsigned short*)(w + 12582912);
    unsigned short* wk_bf = wq_bf + 589824;
    unsigned short* wv_bf = wk_bf + 589824;
    unsigned short* q_ws  = (unsigned short*)(w + 12582912 + 3 * 1179648);
    unsigned short* k_ws  = q_ws + 6291456;
    unsigned short* v_ws  = k_ws + 6291456;

    cvt_all_kernel<<<1968, 256, 0, stream>>>(hs, Wq, Wk, Wv, hs_bf, wq_bf, wk_bf, wv_bf);

    qkv_gemm<<<dim3(64, 18), 256, 0, stream>>>(hs_bf, wq_bf, wk_bf, wv_bf,
                                               bq, bk, bv, q_ws, k_ws, v_ws);

    banded_attn<<<dim3(S_LEN / QB, NH, BATCH), 512, 0, stream>>>(q_ws, k_ws, v_ws, out);
}